// Round 3
// baseline (430.347 us; speedup 1.0000x reference)
//
#include <hip/hip_runtime.h>

#define BB 8
#define SS 1024
#define HH 768
#define EE 9
#define DD 64
#define NCOL (EE * 2 * DD)  // 1152

typedef __bf16 bf16x8 __attribute__((ext_vector_type(8)));
typedef float f32x4 __attribute__((ext_vector_type(4)));

__device__ __forceinline__ unsigned short f2b(float f) {
    unsigned int x = __float_as_uint(f);
    unsigned int r = (x + 0x7fffu + ((x >> 16) & 1u)) >> 16;
    return (unsigned short)r;
}

// ---------------------------------------------------------------------------
// Kernel 0: one-shot fp32 -> bf16 convert of lhs and W into workspace.
// Each element converted exactly once (vs 9x/64x inside the GEMM K-loop).
// ---------------------------------------------------------------------------
__global__ __launch_bounds__(256) void convert_bf16(
    const float* __restrict__ lhs, const float* __restrict__ W,
    unsigned short* __restrict__ lhs_b, unsigned short* __restrict__ W_b) {
    const int NL4 = (BB * SS * HH) / 4;  // 1,572,864 float4s
    const int NW4 = (NCOL * HH) / 4;     //   221,184 float4s
    int i = blockIdx.x * blockDim.x + threadIdx.x;
    if (i < NL4) {
        float4 v = ((const float4*)lhs)[i];
        ushort4 u = {f2b(v.x), f2b(v.y), f2b(v.z), f2b(v.w)};
        ((ushort4*)lhs_b)[i] = u;
    } else {
        int j = i - NL4;
        if (j < NW4) {
            float4 v = ((const float4*)W)[j];
            ushort4 u = {f2b(v.x), f2b(v.y), f2b(v.z), f2b(v.w)};
            ((ushort4*)W_b)[j] = u;
        }
    }
}

// ---------------------------------------------------------------------------
// Kernel 1: C = lhs @ W^T + bias, RoPE, write q/k bf16 to ws [b*E+e][s][d].
// Pure-bf16 128x128 tile, BK=64, 4 waves 2x2, 16x16x32 MFMA. Wave N-span =
// one aligned 64-col (e,q/k) group -> rotate-half partner is acc tile nt+/-2.
// RoPE trig via v_sin/v_cos on revolutions (1/2pi folded into inv-freq).
// ---------------------------------------------------------------------------
#define LDK 72  // 64 + 8 pad (ushorts); row stride 144 B, 16B-aligned
__global__ __launch_bounds__(256) void dense_rope_mfma(
    const unsigned short* __restrict__ A,   // [B*S][H] bf16
    const unsigned short* __restrict__ Wb,  // [1152][H] bf16
    const float* __restrict__ bias,         // [1152]
    unsigned short* __restrict__ q_ws,
    unsigned short* __restrict__ k_ws) {
    __shared__ unsigned short As[128 * LDK];
    __shared__ unsigned short Bs[128 * LDK];

    const int t = threadIdx.x;
    const int lane = t & 63, wave = t >> 6;
    const int quad = lane >> 4, lr = lane & 15;
    const int wm = wave >> 1, wn = wave & 1;
    const int j0 = blockIdx.x * 128;
    const int m0 = blockIdx.y * 128;

    f32x4 acc[4][4] = {};

    for (int kt = 0; kt < HH / 64; ++kt) {
        const int k0 = kt * 64;
        uint4 av[4], bv[4];
#pragma unroll
        for (int i = 0; i < 4; ++i) {
            int idx = t + i * 256;        // 1024 16B chunks per 128x64 bf16 tile
            int row = idx >> 3, c8 = (idx & 7) * 8;
            av[i] = *(const uint4*)&A[(size_t)(m0 + row) * HH + k0 + c8];
            bv[i] = *(const uint4*)&Wb[(size_t)(j0 + row) * HH + k0 + c8];
        }
        __syncthreads();  // previous tile's LDS fully consumed
#pragma unroll
        for (int i = 0; i < 4; ++i) {
            int idx = t + i * 256;
            int row = idx >> 3, c8 = (idx & 7) * 8;
            *(uint4*)&As[row * LDK + c8] = av[i];
            *(uint4*)&Bs[row * LDK + c8] = bv[i];
        }
        __syncthreads();

#pragma unroll
        for (int kh = 0; kh < 2; ++kh) {
            bf16x8 af[4], bf[4];
#pragma unroll
            for (int mt = 0; mt < 4; ++mt)
                af[mt] = *(const bf16x8*)&As[(wm * 64 + mt * 16 + lr) * LDK + kh * 32 + quad * 8];
#pragma unroll
            for (int nt = 0; nt < 4; ++nt)
                bf[nt] = *(const bf16x8*)&Bs[(wn * 64 + nt * 16 + lr) * LDK + kh * 32 + quad * 8];
#pragma unroll
            for (int mt = 0; mt < 4; ++mt)
#pragma unroll
                for (int nt = 0; nt < 4; ++nt)
                    acc[mt][nt] = __builtin_amdgcn_mfma_f32_16x16x32_bf16(
                        af[mt], bf[nt], acc[mt][nt], 0, 0, 0);
        }
    }

    // Epilogue: bias + RoPE in registers, store bf16.
    const int gcol0 = j0 + wn * 64;  // aligned 64-col group
    const int g = gcol0 >> 6;
    const int e = g >> 1;
    unsigned short* dst = (g & 1) ? k_ws : q_ws;
    const int b_idx = m0 >> 10;      // 128 | 1024, uniform per block
    const size_t zbase = (size_t)(b_idx * EE + e) * SS;
    const float L2_1E4_D32 = 0.4152410118609203f;   // log2(10000)/32
    const float INV_2PI = 0.15915494309189535f;

    float bb[4], invrev[4];
#pragma unroll
    for (int nt = 0; nt < 4; ++nt) {
        bb[nt] = bias[gcol0 + nt * 16 + lr];
        int half = (nt * 16 + lr) >> 1;
        invrev[nt] = exp2f(-(float)half * L2_1E4_D32) * INV_2PI;
    }
    const int s0 = (m0 & (SS - 1)) + wm * 64;
#pragma unroll
    for (int mt = 0; mt < 4; ++mt) {
#pragma unroll
        for (int reg = 0; reg < 4; ++reg) {
            const int s = s0 + mt * 16 + quad * 4 + reg;
            float c[4];
#pragma unroll
            for (int nt = 0; nt < 4; ++nt) c[nt] = acc[mt][nt][reg] + bb[nt];
#pragma unroll
            for (int nt = 0; nt < 4; ++nt) {
                float rot = (nt < 2) ? -c[nt + 2] : c[nt - 2];
                float rev = (float)s * invrev[nt];
                rev -= floorf(rev);                       // wrap to [0,1)
                float sv = __builtin_amdgcn_sinf(rev);    // v_sin_f32 (revolutions)
                float cv = __builtin_amdgcn_cosf(rev);
                const int d = nt * 16 + lr;
                dst[(zbase + s) * DD + d] = f2b(c[nt] * cv + rot * sv);
            }
        }
    }
}

// ---------------------------------------------------------------------------
// Kernel 2: logits[z][m][n] = dot(q[z][m], k[z][n]) / 8, pad + causal mask.
// 128x128 tile per block, K=64 staged once (2 MFMA k-steps), direct stores.
// ---------------------------------------------------------------------------
#define LDA2 72  // 64 + 8 pad; row stride 144 B, 16B-aligned
__global__ __launch_bounds__(256) void logits_mfma(
    const unsigned short* __restrict__ q_ws,
    const unsigned short* __restrict__ k_ws,
    const float* __restrict__ mask,  // [B][S]
    float* __restrict__ out) {       // [B*E][S][S]
    __shared__ unsigned short Qs[128 * LDA2];
    __shared__ unsigned short Ks[128 * LDA2];

    const int t = threadIdx.x;
    const int lane = t & 63, wave = t >> 6;
    const int quad = lane >> 4, lr = lane & 15;
    const int wm = wave >> 1, wn = wave & 1;
    const int n0 = blockIdx.x * 128;
    const int m0 = blockIdx.y * 128;
    const int z = blockIdx.z;        // b*E + e
    const int b_idx = z / EE;

    const uint4* qsrc = (const uint4*)(q_ws + ((size_t)z * SS + m0) * DD);
    const uint4* ksrc = (const uint4*)(k_ws + ((size_t)z * SS + n0) * DD);
#pragma unroll
    for (int i = 0; i < 4; ++i) {
        int idx = t + i * 256;       // 1024 16B chunks per 128x64 bf16 tile
        int row = idx >> 3, c8 = (idx & 7) * 8;
        uint4 qv = qsrc[idx];
        uint4 kv = ksrc[idx];
        *(uint4*)&Qs[row * LDA2 + c8] = qv;
        *(uint4*)&Ks[row * LDA2 + c8] = kv;
    }
    __syncthreads();

    f32x4 acc[4][4] = {};
#pragma unroll
    for (int ks = 0; ks < DD; ks += 32) {
        bf16x8 af[4], bf[4];
#pragma unroll
        for (int mt = 0; mt < 4; ++mt)
            af[mt] = *(const bf16x8*)&Qs[(wm * 64 + mt * 16 + lr) * LDA2 + ks + quad * 8];
#pragma unroll
        for (int nt = 0; nt < 4; ++nt)
            bf[nt] = *(const bf16x8*)&Ks[(wn * 64 + nt * 16 + lr) * LDA2 + ks + quad * 8];
#pragma unroll
        for (int mt = 0; mt < 4; ++mt)
#pragma unroll
            for (int nt = 0; nt < 4; ++nt)
                acc[mt][nt] = __builtin_amdgcn_mfma_f32_16x16x32_bf16(
                    af[mt], bf[nt], acc[mt][nt], 0, 0, 0);
    }

    float p[4];
#pragma unroll
    for (int nt = 0; nt < 4; ++nt)
        p[nt] = mask[b_idx * SS + n0 + wn * 64 + nt * 16 + lr];

    float* outz = out + (size_t)z * SS * SS;
#pragma unroll
    for (int mt = 0; mt < 4; ++mt) {
#pragma unroll
        for (int reg = 0; reg < 4; ++reg) {
            const int m = m0 + wm * 64 + mt * 16 + quad * 4 + reg;
#pragma unroll
            for (int nt = 0; nt < 4; ++nt) {
                const int n = n0 + wn * 64 + nt * 16 + lr;
                float v = acc[mt][nt][reg] * 0.125f;
                v = v * p[nt] - (1.0f - p[nt]) * 10000.0f;
                if (n < m) v -= 10000.0f;
                outz[(size_t)m * SS + n] = v;
            }
        }
    }
}

extern "C" void kernel_launch(void* const* d_in, const int* in_sizes, int n_in,
                              void* d_out, int out_size, void* d_ws, size_t ws_size,
                              hipStream_t stream) {
    const float* lhs  = (const float*)d_in[0];  // [8][1024][768]
    const float* mask = (const float*)d_in[1];  // [8][1024]
    const float* W    = (const float*)d_in[2];  // [1152][768]
    const float* bias = (const float*)d_in[3];  // [1152]
    float* out = (float*)d_out;                 // [8][9][1024][1024]

    unsigned short* q_ws  = (unsigned short*)d_ws;
    unsigned short* k_ws  = q_ws + (size_t)BB * EE * SS * DD;   // 4,718,592 each
    unsigned short* lhs_b = k_ws + (size_t)BB * EE * SS * DD;
    unsigned short* W_b   = lhs_b + (size_t)BB * SS * HH;       // 6,291,456

    const int NL4 = (BB * SS * HH) / 4;
    const int NW4 = (NCOL * HH) / 4;
    convert_bf16<<<(NL4 + NW4 + 255) / 256, 256, 0, stream>>>(lhs, W, lhs_b, W_b);

    dim3 g1(NCOL / 128, (BB * SS) / 128);  // 9 x 64
    dense_rope_mfma<<<g1, 256, 0, stream>>>(lhs_b, W_b, bias, q_ws, k_ws);

    dim3 g2(SS / 128, SS / 128, BB * EE);  // 8 x 8 x 72
    logits_mfma<<<g2, 256, 0, stream>>>(q_ws, k_ws, mask, out);
}